// Round 4
// baseline (409.279 us; speedup 1.0000x reference)
//
#include <hip/hip_runtime.h>
#include <cstdint>

#define TSEQ 4096
#define DIMD 1024
#define NBATCH 4
#define MTOT (NBATCH*TSEQ)   // 16384 rows total
#define NST 4                // band subtiles of 128 => min future coverage 385 (tail ~8e-9)
#define PW (NST*128)         // 512 stored band width
#define PTILE (PW*128)       // elements per (b,qt) P tile = 65536

typedef __bf16 bf16;
typedef bf16 bf16x8 __attribute__((ext_vector_type(8)));
typedef bf16 bf16x4 __attribute__((ext_vector_type(4)));
typedef float f32x4 __attribute__((ext_vector_type(4)));

__device__ __forceinline__ void gl2lds16(const void* g, void* l) {
  // async global->LDS, 16B per lane; LDS dest is wave-uniform base + lane*16
  __builtin_amdgcn_global_load_lds(
      (__attribute__((address_space(1))) void*)(g),
      (__attribute__((address_space(3))) void*)(l), 16, 0, 0);
}
__device__ __forceinline__ f32x4 mfma16(bf16x8 a, bf16x8 b, f32x4 c) {
  return __builtin_amdgcn_mfma_f32_16x16x32_bf16(a, b, c, 0, 0, 0);
}

// ---------------- fp32 -> bf16 convert ----------------
__global__ void cvt_kernel(const float* __restrict__ in, bf16* __restrict__ out, int n) {
  int i = (blockIdx.x * 256 + threadIdx.x) * 4;
  if (i >= n) return;
  float4 v = *(const float4*)(in + i);
  bf16x4 o = { (bf16)v.x, (bf16)v.y, (bf16)v.z, (bf16)v.w };
  *(bf16x4*)(out + i) = o;
}

// 4 sources in one dispatch (weights); blockIdx.y selects the pair.
__global__ void cvt4_kernel(const float* __restrict__ s0, const float* __restrict__ s1,
                            const float* __restrict__ s2, const float* __restrict__ s3,
                            bf16* __restrict__ d0, bf16* __restrict__ d1,
                            bf16* __restrict__ d2, bf16* __restrict__ d3) {
  const float* srcs[4] = {s0, s1, s2, s3};
  bf16*        dsts[4] = {d0, d1, d2, d3};
  const float* in = srcs[blockIdx.y];
  bf16* out = dsts[blockIdx.y];
  int i = (blockIdx.x * 256 + threadIdx.x) * 4;
  float4 v = *(const float4*)(in + i);
  bf16x4 o = { (bf16)v.x, (bf16)v.y, (bf16)v.z, (bf16)v.w };
  *(bf16x4*)(out + i) = o;
}

// ---------------- C = A @ B^T  (A[M,K], B[N,K] both row-major bf16) ----------------
// 128x128 tile, 4 waves 2x2, each wave 4x4 16x16x32 MFMAs per K-chunk of 32.
// R3 lesson: keep 16x16 fragment layout — 32x32 tripled LDS bank conflicts.
// split!=0: output col>>10 selects Q/K/V buffer (fused QKV projection).
__global__ void gemm_bt(const bf16* __restrict__ A, const bf16* __restrict__ B,
                        bf16* __restrict__ Cb, float* __restrict__ Cf,
                        const float* __restrict__ scale_ptr, int N, int K, int split,
                        int row_off) {
  __shared__ bf16 As[128*32];
  __shared__ bf16 Bs[128*32];
  const int tid = threadIdx.x;
  const int wave = tid >> 6, lane = tid & 63;
  const int row0 = blockIdx.x * 128 + row_off, col0 = blockIdx.y * 128;
  const int wr = wave >> 1, wc = wave & 1;
  f32x4 acc[4][4] = {};
  const int srow = wave*32 + (lane>>2);
  const int scol = (lane&3)*8;
  const bf16* gA = A + (size_t)(row0 + srow)*K + scol;
  const bf16* gB = B + (size_t)(col0 + srow)*K + scol;
  bf16* lA = As + (wave*32)*32;
  bf16* lB = Bs + (wave*32)*32;
  for (int k0 = 0; k0 < K; k0 += 32) {
    gl2lds16(gA,                lA);
    gl2lds16(gA + (size_t)16*K, lA + 16*32);
    gl2lds16(gB,                lB);
    gl2lds16(gB + (size_t)16*K, lB + 16*32);
    gA += 32; gB += 32;
    __syncthreads();
    bf16x8 af[4], bfr[4];
    #pragma unroll
    for (int i = 0; i < 4; ++i) {
      af[i]  = *(const bf16x8*)(As + (wr*64 + i*16 + (lane&15))*32 + (lane>>4)*8);
      bfr[i] = *(const bf16x8*)(Bs + (wc*64 + i*16 + (lane&15))*32 + (lane>>4)*8);
    }
    #pragma unroll
    for (int i = 0; i < 4; ++i)
      #pragma unroll
      for (int j = 0; j < 4; ++j)
        acc[i][j] = mfma16(af[i], bfr[j], acc[i][j]);
    __syncthreads();
  }
  float sc = scale_ptr ? *scale_ptr : 1.0f;
  #pragma unroll
  for (int i = 0; i < 4; ++i) {
    #pragma unroll
    for (int j = 0; j < 4; ++j) {
      int col  = col0 + wc*64 + j*16 + (lane&15);
      int rowb = row0 + wr*64 + i*16 + (lane>>4)*4;
      #pragma unroll
      for (int r = 0; r < 4; ++r) {
        float v = acc[i][j][r] * sc;
        if (split) {
          size_t idx = ((size_t)(col >> 10) * MTOT + (rowb + r)) * 1024 + (col & 1023);
          Cb[idx] = (bf16)v;
        } else if (Cf) {
          Cf[(size_t)(rowb + r)*N + col] = v;
        } else {
          Cb[(size_t)(rowb + r)*N + col] = (bf16)v;
        }
      }
    }
  }
}

// ---------------- V[b][T][D] -> panel layout Vtt[b][t/32][d][t%32] ----------------
__global__ void transpose_kernel(const bf16* __restrict__ V, bf16* __restrict__ Vt) {
  __shared__ bf16 tile[64][72];   // +8 pad keeps 16B alignment, breaks bank stride
  int b = blockIdx.z;
  int t0 = blockIdx.x * 64, c0 = blockIdx.y * 64;
  int tid = threadIdx.x;
  int r = tid >> 2, cb = (tid & 3) * 16;
  const bf16* src = V + ((size_t)b*TSEQ + t0 + r)*DIMD + c0 + cb;
  *(bf16x8*)&tile[r][cb]     = *(const bf16x8*)src;
  *(bf16x8*)&tile[r][cb + 8] = *(const bf16x8*)(src + 8);
  __syncthreads();
  int cr = tid >> 2, tb = (tid & 3) * 16;
  bf16x8 o0, o1;
  #pragma unroll
  for (int j = 0; j < 8; ++j) { o0[j] = tile[tb+j][cr]; o1[j] = tile[tb+8+j][cr]; }
  int t = t0 + tb;
  bf16* dst = Vt + (((size_t)b*(TSEQ/32) + (t >> 5))*DIMD + c0 + cr)*32 + (t & 31);
  *(bf16x8*)dst       = o0;   // t..t+7
  *(bf16x8*)(dst + 8) = o1;   // t+8..t+15  (same 32-panel: t%32 in {0,16})
}

// ---------------- banded weighted scores, 128x128 tiles ----------------
// P tiled: Pt[b*32+qt][k/32][row 0..127][k%32], k = s - qt*128. Block per (st,qt,b).
__global__ void score_kernel(const bf16* __restrict__ Q, const bf16* __restrict__ Km,
                             bf16* __restrict__ P, const float* __restrict__ dlogit) {
  __shared__ bf16 Qs[128*32];
  __shared__ bf16 Ks[128*32];
  const int st = blockIdx.x, qt = blockIdx.y, b = blockIdx.z;
  const int i0 = qt*128, s0 = i0 + st*128;
  const int tid = threadIdx.x, wave = tid>>6, lane = tid&63;
  const int wr = wave>>1, wc = wave&1;
  bf16* Pp = P + ((size_t)b*(TSEQ/128) + qt)*PTILE;
  if (s0 >= TSEQ) {            // fully out-of-range tile: zero-fill (pv reads full band)
    bf16* base2 = Pp + (size_t)st*4*4096;  // 4 contiguous kt-slabs = 32KB
    bf16x8 z = {};
    #pragma unroll
    for (int v = 0; v < 16; ++v)
      *(bf16x8*)(base2 + (size_t)tid*128 + v*8) = z;
    return;
  }
  f32x4 acc[4][4] = {};
  const int srow = wave*32 + (lane>>2);
  const int scol = (lane&3)*8;
  const bf16* gq = Q + ((size_t)b*TSEQ + i0 + srow)*DIMD + scol;
  int sr1 = s0 + srow;      if (sr1 > TSEQ-1) sr1 = TSEQ-1;   // clamp OOB rows; w=0 masks
  int sr2 = s0 + srow + 16; if (sr2 > TSEQ-1) sr2 = TSEQ-1;
  const bf16* gk1 = Km + ((size_t)b*TSEQ + sr1)*DIMD + scol;
  const bf16* gk2 = Km + ((size_t)b*TSEQ + sr2)*DIMD + scol;
  bf16* lq = Qs + (wave*32)*32;
  bf16* lk = Ks + (wave*32)*32;
  for (int k0 = 0; k0 < DIMD; k0 += 32) {
    gl2lds16(gq,            lq);
    gl2lds16(gq + 16*DIMD,  lq + 16*32);
    gl2lds16(gk1,           lk);
    gl2lds16(gk2,           lk + 16*32);
    gq += 32; gk1 += 32; gk2 += 32;
    __syncthreads();
    bf16x8 af[4], bfr[4];
    #pragma unroll
    for (int i = 0; i < 4; ++i) {
      af[i]  = *(const bf16x8*)(Qs + (wr*64 + i*16 + (lane&15))*32 + (lane>>4)*8);
      bfr[i] = *(const bf16x8*)(Ks + (wc*64 + i*16 + (lane&15))*32 + (lane>>4)*8);
    }
    #pragma unroll
    for (int i = 0; i < 4; ++i)
      #pragma unroll
      for (int j = 0; j < 4; ++j)
        acc[i][j] = mfma16(af[i], bfr[j], acc[i][j]);
    __syncthreads();
  }
  float decay = 1.0f / (1.0f + expf(-*dlogit));
  float l2d = log2f(decay);
  #pragma unroll
  for (int i = 0; i < 4; ++i) {
    #pragma unroll
    for (int j = 0; j < 4; ++j) {
      int col = wc*64 + j*16 + (lane&15);           // 0..127 within st
      int s = s0 + col;
      int kt = st*4 + (col >> 5);
      #pragma unroll
      for (int r = 0; r < 4; ++r) {
        int row = wr*64 + i*16 + (lane>>4)*4 + r;
        int t = i0 + row;
        float w = (s > t && s < TSEQ) ? exp2f((float)(s - t - 1) * l2d) : 0.0f;
        Pp[(size_t)kt*4096 + row*32 + (col & 31)] = (bf16)(acc[i][j][r] * 0.03125f * w);
      }
    }
  }
}

// ---------------- R[128x128 tile] = P_band @ V  (tiled P, panel Vtt) ----------------
__global__ void pv_kernel(const bf16* __restrict__ P, const bf16* __restrict__ Vt,
                          bf16* __restrict__ R) {
  __shared__ bf16 Ps[128*32];
  __shared__ bf16 Vs[128*32];
  const int cb = blockIdx.x, qt = blockIdx.y, b = blockIdx.z;
  const int i0 = qt*128, c0 = cb*128;
  const int tid = threadIdx.x, wave = tid>>6, lane = tid&63;
  const int wr = wave>>1, wc = wave&1;
  f32x4 acc[4][4] = {};
  const bf16* Pp = P + ((size_t)b*(TSEQ/128) + qt)*PTILE;
  // contiguous staging: each wave stages 1KB+1KB from the [128][32] kt-slab
  const bf16* gp = Pp + wave*1024 + (size_t)lane*8;
  bf16* lp = Ps + (wave*32)*32;
  bf16* lv = Vs + (wave*32)*32;
  const size_t voff = (size_t)(c0)*32 + wave*1024 + (size_t)lane*8;
  for (int k0 = 0; k0 < PW; k0 += 32) {
    gl2lds16(gp,       lp);
    gl2lds16(gp + 512, lp + 16*32);
    gp += 4096;
    int s0k = i0 + k0;
    int tc = (s0k < TSEQ) ? (s0k >> 5) : 0;       // OOB k: P is 0 there, any valid panel
    const bf16* gv = Vt + ((size_t)b*(TSEQ/32) + tc)*DIMD*32 + voff;
    gl2lds16(gv,       lv);
    gl2lds16(gv + 512, lv + 16*32);
    __syncthreads();
    bf16x8 af[4], bfr[4];
    #pragma unroll
    for (int i = 0; i < 4; ++i) {
      af[i]  = *(const bf16x8*)(Ps + (wr*64 + i*16 + (lane&15))*32 + (lane>>4)*8);
      bfr[i] = *(const bf16x8*)(Vs + (wc*64 + i*16 + (lane&15))*32 + (lane>>4)*8);
    }
    #pragma unroll
    for (int i = 0; i < 4; ++i)
      #pragma unroll
      for (int j = 0; j < 4; ++j)
        acc[i][j] = mfma16(af[i], bfr[j], acc[i][j]);
    __syncthreads();
  }
  #pragma unroll
  for (int i = 0; i < 4; ++i)
    #pragma unroll
    for (int j = 0; j < 4; ++j) {
      int col  = c0 + wc*64 + j*16 + (lane&15);
      int rowb = i0 + wr*64 + i*16 + (lane>>4)*4;
      #pragma unroll
      for (int r = 0; r < 4; ++r)
        R[((size_t)b*TSEQ + rowb + r)*DIMD + col] = (bf16)acc[i][j][r];
    }
}

extern "C" void kernel_launch(void* const* d_in, const int* in_sizes, int n_in,
                              void* d_out, int out_size, void* d_ws, size_t ws_size,
                              hipStream_t stream) {
  const float* x      = (const float*)d_in[0];
  const float* Wq     = (const float*)d_in[1];
  const float* Wk     = (const float*)d_in[2];
  const float* Wv     = (const float*)d_in[3];
  const float* Wo     = (const float*)d_in[4];
  const float* dlogit = (const float*)d_in[5];
  const float* oscale = (const float*)d_in[6];
  float* out = (float*)d_out;

  char* ws = (char*)d_ws;
  size_t off = 0;
  auto alloc = [&](size_t bytes) -> void* {
    void* p = ws + off; off += (bytes + 255) & ~(size_t)255; return p;
  };
  const size_t XN = (size_t)MTOT * DIMD;              // 16,777,216 elements
  const size_t WN = (size_t)DIMD * DIMD;
  bf16* xb   = (bf16*)alloc(XN * 2);                  // 32 MB
  bf16* QKVb = (bf16*)alloc(3 * XN * 2);              // 96 MB: Q | K | V
  bf16* Vtb  = (bf16*)alloc(XN * 2);                  // 32 MB (panel layout)
  bf16* Wcat = (bf16*)alloc(3 * WN * 2);              // 6 MB: Wq | Wk | Wv rows
  bf16* Wob  = (bf16*)alloc(WN * 2);                  // 2 MB
  if (ws_size < off) return;                          // total 168 MB
  bf16* Qb = QKVb;
  bf16* Kb = QKVb + XN;
  bf16* Vb = QKVb + 2*XN;
  bf16* Pb = Vb;   // alias: V region dead after transpose; P = 16.8 MB <= 32 MB
  bf16* Rb = xb;   // alias: x region dead after QKV projection

  // fp32 -> bf16
  cvt_kernel<<<dim3((unsigned)(XN/1024)), dim3(256), 0, stream>>>(x, xb, (int)XN);
  cvt4_kernel<<<dim3((unsigned)(WN/1024), 4), dim3(256), 0, stream>>>(
      Wq, Wk, Wv, Wo, Wcat, Wcat + WN, Wcat + 2*WN, Wob);

  // fused QKV projection, split into two M-halves (visibility + exact 6 blocks/CU)
  gemm_bt<<<dim3(MTOT/256, 3*DIMD/128), dim3(256), 0, stream>>>(
      xb, Wcat, QKVb, nullptr, nullptr, 3*DIMD, DIMD, 1, 0);
  gemm_bt<<<dim3(MTOT/256, 3*DIMD/128), dim3(256), 0, stream>>>(
      xb, Wcat, QKVb, nullptr, nullptr, 3*DIMD, DIMD, 1, MTOT/2);

  // V -> panel layout for contiguous pv staging
  transpose_kernel<<<dim3(TSEQ/64, DIMD/64, NBATCH), dim3(256), 0, stream>>>(Vb, Vtb);

  // banded weighted scores (128x128 tiles, 4-subtile band, tiled P layout)
  score_kernel<<<dim3(NST, TSEQ/128, NBATCH), dim3(256), 0, stream>>>(Qb, Kb, Pb, dlogit);

  // P @ V
  pv_kernel<<<dim3(DIMD/128, TSEQ/128, NBATCH), dim3(256), 0, stream>>>(Pb, Vtb, Rb);

  // output projection with out_scale, fp32 out
  gemm_bt<<<dim3(MTOT/128, DIMD/128), dim3(256), 0, stream>>>(
      Rb, Wob, nullptr, out, oscale, DIMD, DIMD, 0, 0);
}

// Round 5
// 400.401 us; speedup vs baseline: 1.0222x; 1.0222x over previous
//
#include <hip/hip_runtime.h>
#include <cstdint>

#define TSEQ 4096
#define DIMD 1024
#define NBATCH 4
#define MTOT (NBATCH*TSEQ)   // 16384 rows total
#define NST 4                // band subtiles of 128 => min future coverage 385 (tail ~8e-9)
#define PW (NST*128)         // 512 stored band width
#define PTILE (PW*128)       // elements per (b,qt) P tile = 65536

typedef __bf16 bf16;
typedef bf16 bf16x8 __attribute__((ext_vector_type(8)));
typedef bf16 bf16x4 __attribute__((ext_vector_type(4)));
typedef float f32x4 __attribute__((ext_vector_type(4)));

__device__ __forceinline__ void gl2lds16(const void* g, void* l) {
  // async global->LDS, 16B per lane; LDS dest is wave-uniform base + lane*16
  __builtin_amdgcn_global_load_lds(
      (__attribute__((address_space(1))) void*)(g),
      (__attribute__((address_space(3))) void*)(l), 16, 0, 0);
}
__device__ __forceinline__ f32x4 mfma16(bf16x8 a, bf16x8 b, f32x4 c) {
  return __builtin_amdgcn_mfma_f32_16x16x32_bf16(a, b, c, 0, 0, 0);
}

// ---------------- fp32 -> bf16 convert ----------------
__global__ void cvt_kernel(const float* __restrict__ in, bf16* __restrict__ out, int n) {
  int i = (blockIdx.x * 256 + threadIdx.x) * 4;
  if (i >= n) return;
  float4 v = *(const float4*)(in + i);
  bf16x4 o = { (bf16)v.x, (bf16)v.y, (bf16)v.z, (bf16)v.w };
  *(bf16x4*)(out + i) = o;
}

// 4 sources in one dispatch (weights); blockIdx.y selects the pair.
__global__ void cvt4_kernel(const float* __restrict__ s0, const float* __restrict__ s1,
                            const float* __restrict__ s2, const float* __restrict__ s3,
                            bf16* __restrict__ d0, bf16* __restrict__ d1,
                            bf16* __restrict__ d2, bf16* __restrict__ d3) {
  const float* srcs[4] = {s0, s1, s2, s3};
  bf16*        dsts[4] = {d0, d1, d2, d3};
  const float* in = srcs[blockIdx.y];
  bf16* out = dsts[blockIdx.y];
  int i = (blockIdx.x * 256 + threadIdx.x) * 4;
  float4 v = *(const float4*)(in + i);
  bf16x4 o = { (bf16)v.x, (bf16)v.y, (bf16)v.z, (bf16)v.w };
  *(bf16x4*)(out + i) = o;
}

// ---------------- C = A @ B^T  (A[M,K], B[N,K] both row-major bf16) ----------------
// 128x128 tile, 4 waves 2x2, BK=64 as TWO BK=32 slabs: identical known-good
// fragment addressing (R3 lesson: don't touch the LDS read pattern), but 32
// MFMAs per barrier pair instead of 16 — halves the vmcnt(0)+s_barrier drains.
// split!=0: output col>>10 selects Q/K/V buffer (fused QKV projection).
__global__ void gemm_bt(const bf16* __restrict__ A, const bf16* __restrict__ B,
                        bf16* __restrict__ Cb, float* __restrict__ Cf,
                        const float* __restrict__ scale_ptr, int N, int K, int split) {
  __shared__ bf16 As[2][128*32];
  __shared__ bf16 Bs[2][128*32];
  const int tid = threadIdx.x;
  const int wave = tid >> 6, lane = tid & 63;
  const int row0 = blockIdx.x * 128, col0 = blockIdx.y * 128;
  const int wr = wave >> 1, wc = wave & 1;
  f32x4 acc[4][4] = {};
  // staging: each issue = 16 rows x 32 cols = 512 contiguous LDS elems in one slab
  const int srow = wave*32 + (lane>>2);
  const int scol = (lane&3)*8;
  const bf16* gA = A + (size_t)(row0 + srow)*K + scol;
  const bf16* gB = B + (size_t)(col0 + srow)*K + scol;
  for (int k0 = 0; k0 < K; k0 += 64) {
    #pragma unroll
    for (int s = 0; s < 2; ++s)
      #pragma unroll
      for (int h = 0; h < 2; ++h) {
        gl2lds16(gA + (size_t)(h*16)*K + s*32, &As[s][(wave*32 + h*16)*32]);
        gl2lds16(gB + (size_t)(h*16)*K + s*32, &Bs[s][(wave*32 + h*16)*32]);
      }
    gA += 64; gB += 64;
    __syncthreads();
    #pragma unroll
    for (int s = 0; s < 2; ++s) {
      bf16x8 af[4], bfr[4];
      #pragma unroll
      for (int i = 0; i < 4; ++i) {
        af[i]  = *(const bf16x8*)(&As[s][0] + (wr*64 + i*16 + (lane&15))*32 + (lane>>4)*8);
        bfr[i] = *(const bf16x8*)(&Bs[s][0] + (wc*64 + i*16 + (lane&15))*32 + (lane>>4)*8);
      }
      #pragma unroll
      for (int i = 0; i < 4; ++i)
        #pragma unroll
        for (int j = 0; j < 4; ++j)
          acc[i][j] = mfma16(af[i], bfr[j], acc[i][j]);
    }
    __syncthreads();
  }
  float sc = scale_ptr ? *scale_ptr : 1.0f;
  #pragma unroll
  for (int i = 0; i < 4; ++i) {
    #pragma unroll
    for (int j = 0; j < 4; ++j) {
      int col  = col0 + wc*64 + j*16 + (lane&15);
      int rowb = row0 + wr*64 + i*16 + (lane>>4)*4;
      #pragma unroll
      for (int r = 0; r < 4; ++r) {
        float v = acc[i][j][r] * sc;
        if (split) {
          size_t idx = ((size_t)(col >> 10) * MTOT + (rowb + r)) * 1024 + (col & 1023);
          Cb[idx] = (bf16)v;
        } else if (Cf) {
          Cf[(size_t)(rowb + r)*N + col] = v;
        } else {
          Cb[(size_t)(rowb + r)*N + col] = (bf16)v;
        }
      }
    }
  }
}

// ---------------- V[b][T][D] -> panel layout Vtt[b][t/32][d][t%32] ----------------
__global__ void transpose_kernel(const bf16* __restrict__ V, bf16* __restrict__ Vt) {
  __shared__ bf16 tile[64][72];   // +8 pad keeps 16B alignment, breaks bank stride
  int b = blockIdx.z;
  int t0 = blockIdx.x * 64, c0 = blockIdx.y * 64;
  int tid = threadIdx.x;
  int r = tid >> 2, cb = (tid & 3) * 16;
  const bf16* src = V + ((size_t)b*TSEQ + t0 + r)*DIMD + c0 + cb;
  *(bf16x8*)&tile[r][cb]     = *(const bf16x8*)src;
  *(bf16x8*)&tile[r][cb + 8] = *(const bf16x8*)(src + 8);
  __syncthreads();
  int cr = tid >> 2, tb = (tid & 3) * 16;
  bf16x8 o0, o1;
  #pragma unroll
  for (int j = 0; j < 8; ++j) { o0[j] = tile[tb+j][cr]; o1[j] = tile[tb+8+j][cr]; }
  int t = t0 + tb;
  bf16* dst = Vt + (((size_t)b*(TSEQ/32) + (t >> 5))*DIMD + c0 + cr)*32 + (t & 31);
  *(bf16x8*)dst       = o0;   // t..t+7
  *(bf16x8*)(dst + 8) = o1;   // t+8..t+15  (same 32-panel: t%32 in {0,16})
}

// ---------------- banded weighted scores, 128x128 tiles ----------------
// P tiled: Pt[b*32+qt][k/32][row 0..127][k%32], k = s - qt*128. Block per (st,qt,b).
__global__ void score_kernel(const bf16* __restrict__ Q, const bf16* __restrict__ Km,
                             bf16* __restrict__ P, const float* __restrict__ dlogit) {
  __shared__ bf16 Qs[128*32];
  __shared__ bf16 Ks[128*32];
  const int st = blockIdx.x, qt = blockIdx.y, b = blockIdx.z;
  const int i0 = qt*128, s0 = i0 + st*128;
  const int tid = threadIdx.x, wave = tid>>6, lane = tid&63;
  const int wr = wave>>1, wc = wave&1;
  bf16* Pp = P + ((size_t)b*(TSEQ/128) + qt)*PTILE;
  if (s0 >= TSEQ) {            // fully out-of-range tile: zero-fill (pv reads full band)
    bf16* base2 = Pp + (size_t)st*4*4096;  // 4 contiguous kt-slabs = 32KB
    bf16x8 z = {};
    #pragma unroll
    for (int v = 0; v < 16; ++v)
      *(bf16x8*)(base2 + (size_t)tid*128 + v*8) = z;
    return;
  }
  f32x4 acc[4][4] = {};
  const int srow = wave*32 + (lane>>2);
  const int scol = (lane&3)*8;
  const bf16* gq = Q + ((size_t)b*TSEQ + i0 + srow)*DIMD + scol;
  int sr1 = s0 + srow;      if (sr1 > TSEQ-1) sr1 = TSEQ-1;   // clamp OOB rows; w=0 masks
  int sr2 = s0 + srow + 16; if (sr2 > TSEQ-1) sr2 = TSEQ-1;
  const bf16* gk1 = Km + ((size_t)b*TSEQ + sr1)*DIMD + scol;
  const bf16* gk2 = Km + ((size_t)b*TSEQ + sr2)*DIMD + scol;
  bf16* lq = Qs + (wave*32)*32;
  bf16* lk = Ks + (wave*32)*32;
  for (int k0 = 0; k0 < DIMD; k0 += 32) {
    gl2lds16(gq,            lq);
    gl2lds16(gq + 16*DIMD,  lq + 16*32);
    gl2lds16(gk1,           lk);
    gl2lds16(gk2,           lk + 16*32);
    gq += 32; gk1 += 32; gk2 += 32;
    __syncthreads();
    bf16x8 af[4], bfr[4];
    #pragma unroll
    for (int i = 0; i < 4; ++i) {
      af[i]  = *(const bf16x8*)(Qs + (wr*64 + i*16 + (lane&15))*32 + (lane>>4)*8);
      bfr[i] = *(const bf16x8*)(Ks + (wc*64 + i*16 + (lane&15))*32 + (lane>>4)*8);
    }
    #pragma unroll
    for (int i = 0; i < 4; ++i)
      #pragma unroll
      for (int j = 0; j < 4; ++j)
        acc[i][j] = mfma16(af[i], bfr[j], acc[i][j]);
    __syncthreads();
  }
  float decay = 1.0f / (1.0f + expf(-*dlogit));
  float l2d = log2f(decay);
  #pragma unroll
  for (int i = 0; i < 4; ++i) {
    #pragma unroll
    for (int j = 0; j < 4; ++j) {
      int col = wc*64 + j*16 + (lane&15);           // 0..127 within st
      int s = s0 + col;
      int kt = st*4 + (col >> 5);
      #pragma unroll
      for (int r = 0; r < 4; ++r) {
        int row = wr*64 + i*16 + (lane>>4)*4 + r;
        int t = i0 + row;
        float w = (s > t && s < TSEQ) ? exp2f((float)(s - t - 1) * l2d) : 0.0f;
        Pp[(size_t)kt*4096 + row*32 + (col & 31)] = (bf16)(acc[i][j][r] * 0.03125f * w);
      }
    }
  }
}

// ---------------- R[128x128 tile] = P_band @ V  (tiled P, panel Vtt) ----------------
__global__ void pv_kernel(const bf16* __restrict__ P, const bf16* __restrict__ Vt,
                          bf16* __restrict__ R) {
  __shared__ bf16 Ps[128*32];
  __shared__ bf16 Vs[128*32];
  const int cb = blockIdx.x, qt = blockIdx.y, b = blockIdx.z;
  const int i0 = qt*128, c0 = cb*128;
  const int tid = threadIdx.x, wave = tid>>6, lane = tid&63;
  const int wr = wave>>1, wc = wave&1;
  f32x4 acc[4][4] = {};
  const bf16* Pp = P + ((size_t)b*(TSEQ/128) + qt)*PTILE;
  // contiguous staging: each wave stages 1KB+1KB from the [128][32] kt-slab
  const bf16* gp = Pp + wave*1024 + (size_t)lane*8;
  bf16* lp = Ps + (wave*32)*32;
  bf16* lv = Vs + (wave*32)*32;
  const size_t voff = (size_t)(c0)*32 + wave*1024 + (size_t)lane*8;
  for (int k0 = 0; k0 < PW; k0 += 32) {
    gl2lds16(gp,       lp);
    gl2lds16(gp + 512, lp + 16*32);
    gp += 4096;
    int s0k = i0 + k0;
    int tc = (s0k < TSEQ) ? (s0k >> 5) : 0;       // OOB k: P is 0 there, any valid panel
    const bf16* gv = Vt + ((size_t)b*(TSEQ/32) + tc)*DIMD*32 + voff;
    gl2lds16(gv,       lv);
    gl2lds16(gv + 512, lv + 16*32);
    __syncthreads();
    bf16x8 af[4], bfr[4];
    #pragma unroll
    for (int i = 0; i < 4; ++i) {
      af[i]  = *(const bf16x8*)(Ps + (wr*64 + i*16 + (lane&15))*32 + (lane>>4)*8);
      bfr[i] = *(const bf16x8*)(Vs + (wc*64 + i*16 + (lane&15))*32 + (lane>>4)*8);
    }
    #pragma unroll
    for (int i = 0; i < 4; ++i)
      #pragma unroll
      for (int j = 0; j < 4; ++j)
        acc[i][j] = mfma16(af[i], bfr[j], acc[i][j]);
    __syncthreads();
  }
  #pragma unroll
  for (int i = 0; i < 4; ++i)
    #pragma unroll
    for (int j = 0; j < 4; ++j) {
      int col  = c0 + wc*64 + j*16 + (lane&15);
      int rowb = i0 + wr*64 + i*16 + (lane>>4)*4;
      #pragma unroll
      for (int r = 0; r < 4; ++r)
        R[((size_t)b*TSEQ + rowb + r)*DIMD + col] = (bf16)acc[i][j][r];
    }
}

extern "C" void kernel_launch(void* const* d_in, const int* in_sizes, int n_in,
                              void* d_out, int out_size, void* d_ws, size_t ws_size,
                              hipStream_t stream) {
  const float* x      = (const float*)d_in[0];
  const float* Wq     = (const float*)d_in[1];
  const float* Wk     = (const float*)d_in[2];
  const float* Wv     = (const float*)d_in[3];
  const float* Wo     = (const float*)d_in[4];
  const float* dlogit = (const float*)d_in[5];
  const float* oscale = (const float*)d_in[6];
  float* out = (float*)d_out;

  char* ws = (char*)d_ws;
  size_t off = 0;
  auto alloc = [&](size_t bytes) -> void* {
    void* p = ws + off; off += (bytes + 255) & ~(size_t)255; return p;
  };
  const size_t XN = (size_t)MTOT * DIMD;              // 16,777,216 elements
  const size_t WN = (size_t)DIMD * DIMD;
  bf16* xb   = (bf16*)alloc(XN * 2);                  // 32 MB
  bf16* QKVb = (bf16*)alloc(3 * XN * 2);              // 96 MB: Q | K | V
  bf16* Vtb  = (bf16*)alloc(XN * 2);                  // 32 MB (panel layout)
  bf16* Wcat = (bf16*)alloc(3 * WN * 2);              // 6 MB: Wq | Wk | Wv rows
  bf16* Wob  = (bf16*)alloc(WN * 2);                  // 2 MB
  if (ws_size < off) return;                          // total 168 MB
  bf16* Qb = QKVb;
  bf16* Kb = QKVb + XN;
  bf16* Vb = QKVb + 2*XN;
  bf16* Pb = Vb;   // alias: V region dead after transpose; P = 16.8 MB <= 32 MB
  bf16* Rb = xb;   // alias: x region dead after QKV projection

  // fp32 -> bf16
  cvt_kernel<<<dim3((unsigned)(XN/1024)), dim3(256), 0, stream>>>(x, xb, (int)XN);
  cvt4_kernel<<<dim3((unsigned)(WN/1024), 4), dim3(256), 0, stream>>>(
      Wq, Wk, Wv, Wo, Wcat, Wcat + WN, Wcat + 2*WN, Wob);

  // fused QKV projection: [16384,1024] @ [3072,1024]^T -> split Q/K/V buffers
  gemm_bt<<<dim3(MTOT/128, 3*DIMD/128), dim3(256), 0, stream>>>(
      xb, Wcat, QKVb, nullptr, nullptr, 3*DIMD, DIMD, 1);

  // V -> panel layout for contiguous pv staging
  transpose_kernel<<<dim3(TSEQ/64, DIMD/64, NBATCH), dim3(256), 0, stream>>>(Vb, Vtb);

  // banded weighted scores (128x128 tiles, 4-subtile band, tiled P layout)
  score_kernel<<<dim3(NST, TSEQ/128, NBATCH), dim3(256), 0, stream>>>(Qb, Kb, Pb, dlogit);

  // P @ V
  pv_kernel<<<dim3(DIMD/128, TSEQ/128, NBATCH), dim3(256), 0, stream>>>(Pb, Vtb, Rb);

  // output projection with out_scale, fp32 out
  gemm_bt<<<dim3(MTOT/128, DIMD/128), dim3(256), 0, stream>>>(
      Rb, Wob, nullptr, out, oscale, DIMD, DIMD, 0);
}